// Round 10
// baseline (1013.155 us; speedup 1.0000x reference)
//
#include <hip/hip_runtime.h>
#include <cstdint>

typedef unsigned short u16;
typedef __attribute__((ext_vector_type(8))) short short8;
typedef __attribute__((ext_vector_type(4))) float f32x4;

#define AS1 __attribute__((address_space(1)))
#define AS3 __attribute__((address_space(3)))

#define BB 4
#define SS 8192
#define EE 1024
#define HH 16
#define DD 64
#define LL 64
#define CANDN 96

__device__ __forceinline__ void async16(const void* g, void* l) {
  __builtin_amdgcn_global_load_lds((const AS1 uint32_t*)g, (AS3 uint32_t*)l, 16, 0, 0);
}
__device__ __forceinline__ u16 f2b(float f) {  // RNE fp32 -> bf16
  uint32_t u = __float_as_uint(f);
  return (u16)((u + 0x7fffu + ((u >> 16) & 1u)) >> 16);
}
__device__ __forceinline__ float b2f(u16 h) { return __uint_as_float(((uint32_t)h) << 16); }

// ---------------- fp32 -> bf16 bulk convert (n divisible by 4) ----------------
__global__ __launch_bounds__(256) void cvt_bf16_k(const float* __restrict__ in, u16* __restrict__ out, int n4) {
  int i = blockIdx.x * 256 + threadIdx.x;
  if (i >= n4) return;
  float4 v = ((const float4*)in)[i];
  ushort4 o;
  o.x = f2b(v.x); o.y = f2b(v.y); o.z = f2b(v.z); o.w = f2b(v.w);
  ((ushort4*)out)[i] = o;
}

// ---------------- NT GEMM v4 (gemm128): occupancy + deep counted prefetch ----------------
// C[m,n] = sum_k A[m,k]*W[n,k] + bias[n]. Tile 128x128, BK=32, 256 threads = 4 waves
// (2m x 2n), acc[4][4]/wave, 16 MFMA/tile. LDS = 4 buffers x 16 KB = 64 KB -> 2 blocks/CU
// (R9 post-mortem: 1-block/CU lockstep + 2-tile prefetch was the stall, not the LDS drain).
// Pipeline: stage tile t+3 at top of tile t into buf[(t+3)&3] (holds t-1's data; its
// ds_reads retired before t-1's closing barrier). Wait-for-t+1 is issued 3 tile-bodies
// ahead (~>900 cyc) and the second block/CU covers residual stalls (m114 TLP overlap).
// Ledger (4 loads/thread/tile): prologue T0,T1,T2 (12 loads) -> vmcnt(8) = T0 landed.
// Boundary entering t+1: issued through min(t+3,NT-1); vmcnt(4*lead), lead = min(t+3,NT-1)
// -(t+1) in {2,1,0} -> 8/4/0. vmcnt completes in issue order (m135).
// LDS granule-XOR swizzle (tid&3)^((row>>1)&3) on pre-swizzled global SOURCE (rule #21),
// read granule quad^((r>>1)&3) -- R0's harness-proven mapping (0 bank conflicts).
// Dual pointer-set: by < mt0 -> set0 else set1 (merges Q+K projections into one dispatch;
// also makes the merged dispatch big enough to surface in rocprof top-5 past the fills).
// Optional scA epilogue (K-proj): per row, per head (wave's 64 cols = 1 head), 16-lane
// shuffle-reduce of sum((v+bias)^2), one atomicAdd(sqrt/16) -> replaces scores_k.
__global__ __launch_bounds__(256) void gemm128(
    const u16* __restrict__ A0, const u16* __restrict__ W0, const float* __restrict__ b0,
    float* __restrict__ Cf0, u16* __restrict__ Cb0, float* __restrict__ sc0,
    const u16* __restrict__ A1, const u16* __restrict__ W1, const float* __restrict__ b1,
    float* __restrict__ Cf1, u16* __restrict__ Cb1, float* __restrict__ sc1,
    int mt0, int K) {
  extern __shared__ __align__(16) u16 lds_[];  // [4][8192]: per buffer A 4096 + B 4096 u16
  const int tid = threadIdx.x;
  const int wv = tid >> 6, lane = tid & 63;
  const int quad = lane >> 4, l15 = lane & 15;
  const int wm = wv >> 1, wn = wv & 1;   // 2x2 waves; per-wave out 64x64

  const int nwg = gridDim.x * gridDim.y;
  int g = blockIdx.y * gridDim.x + blockIdx.x;
  int bx = blockIdx.x, by = blockIdx.y;
  if ((nwg & 7) == 0) {
    const int chunk = nwg >> 3;
    const int v = (g & 7) * chunk + (g >> 3);
    bx = v % gridDim.x;
    by = v / gridDim.x;
  }
  const u16* A; const u16* W; const float* bias; float* Cf; u16* Cb; float* scA;
  int myb;
  if (by < mt0) { A = A0; W = W0; bias = b0; Cf = Cf0; Cb = Cb0; scA = sc0; myb = by; }
  else          { A = A1; W = W1; bias = b1; Cf = Cf1; Cb = Cb1; scA = sc1; myb = by - mt0; }
  const int mt = myb * 128, nt = bx * 128;

  const int row0 = tid >> 2, cg0 = (tid & 3) ^ ((row0 >> 1) & 3);
  const int row1 = 64 + row0, cg1 = (tid & 3) ^ ((row1 >> 1) & 3);
  const u16* gA0 = A + (size_t)(mt + row0) * K + cg0 * 8;
  const u16* gA1 = A + (size_t)(mt + row1) * K + cg1 * 8;
  const u16* gB0 = W + (size_t)(nt + row0) * K + cg0 * 8;
  const u16* gB1 = W + (size_t)(nt + row1) * K + cg1 * 8;

  auto STAGE = [&](int tile, int pb) {
    const int off = tile * 32;
    u16* base = lds_ + pb * 8192;
    async16(gA0 + off, base + tid * 8);
    async16(gA1 + off, base + 2048 + tid * 8);
    async16(gB0 + off, base + 4096 + tid * 8);
    async16(gB1 + off, base + 6144 + tid * 8);
  };

  f32x4 acc[4][4];
#pragma unroll
  for (int i = 0; i < 4; i++)
#pragma unroll
    for (int j = 0; j < 4; j++) acc[i][j] = (f32x4){0.f, 0.f, 0.f, 0.f};

  const int NT = K >> 5;  // BK=32; NT >= 4 (all calls K=1024 -> 32)
  STAGE(0, 0);
  STAGE(1, 1);
  STAGE(2, 2);
  asm volatile("s_waitcnt vmcnt(8)\n\ts_barrier" ::: "memory");  // T0 landed; T1,T2 in flight

  for (int t = 0; t < NT; ++t) {
    if (t + 3 < NT) STAGE(t + 3, (t + 3) & 3);  // target buf consumed at t-1 (reads retired)
    const short8* pA = (const short8*)(lds_ + (t & 3) * 8192);
    const short8* pB = pA + 512;  // B at +4096 u16
    short8 af[4], bfr[4];
#pragma unroll
    for (int i = 0; i < 4; i++) {
      const int r = 64 * wm + 16 * i + l15;
      af[i] = pA[r * 4 + (quad ^ ((r >> 1) & 3))];
      const int rb = 64 * wn + 16 * i + l15;
      bfr[i] = pB[rb * 4 + (quad ^ ((rb >> 1) & 3))];
    }
    __builtin_amdgcn_s_setprio(1);
#pragma unroll
    for (int i = 0; i < 4; i++)
#pragma unroll
      for (int j = 0; j < 4; j++)
        acc[i][j] = __builtin_amdgcn_mfma_f32_16x16x32_bf16(af[i], bfr[j], acc[i][j], 0, 0, 0);
    __builtin_amdgcn_s_setprio(0);
    if (t + 1 < NT) {
      if (t + 3 < NT)      { asm volatile("s_waitcnt vmcnt(8)\n\ts_barrier" ::: "memory"); }
      else if (t + 2 < NT) { asm volatile("s_waitcnt vmcnt(4)\n\ts_barrier" ::: "memory"); }
      else                 { asm volatile("s_waitcnt vmcnt(0)\n\ts_barrier" ::: "memory"); }
    }
  }

  float bs[4];
#pragma unroll
  for (int j = 0; j < 4; j++) bs[j] = bias[nt + 64 * wn + 16 * j + l15];
#pragma unroll
  for (int i = 0; i < 4; i++) {
#pragma unroll
    for (int r = 0; r < 4; r++) {
      const int gm = mt + 64 * wm + 16 * i + quad * 4 + r;
      float nrm = 0.f;
#pragma unroll
      for (int j = 0; j < 4; j++) {
        float v = acc[i][j][r] + bs[j];
        const int gn = nt + 64 * wn + 16 * j + l15;
        if (Cf) Cf[(size_t)gm * EE + gn] = v;
        if (Cb) Cb[(size_t)gm * EE + gn] = f2b(v);
        nrm += v * v;
      }
      if (scA) {
#pragma unroll
        for (int m = 1; m < 16; m <<= 1) nrm += __shfl_xor(nrm, m, 64);
        if (l15 == 0) atomicAdd(&scA[gm], sqrtf(nrm) * (1.f / 16.f));
      }
    }
  }
}

// ---------------- stage-1 topk: exact top-96 set per batch (order-free) ----------------
#define TKT 1024
#define EQCAP 256
__global__ __launch_bounds__(TKT) void topk1_k(const float* __restrict__ sc, int* __restrict__ cand) {
  const int b = blockIdx.x;
  __shared__ uint32_t s[SS];
  __shared__ int wsum[TKT / 64];
  __shared__ int cnt_sh;
  __shared__ int counter, eqcount;
  __shared__ int eqbuf[EQCAP];
  const int tid = threadIdx.x;
  const int lane = tid & 63, wv = tid >> 6;
  for (int i = tid; i < SS; i += TKT) s[i] = __float_as_uint(sc[b * SS + i]);
  if (tid == 0) { counter = 0; eqcount = 0; }
  __syncthreads();

  uint32_t lo = 0u, hi = 0x7f7fffffu;
  while (lo < hi) {
    uint32_t mid = lo + ((hi - lo + 1) >> 1);
    int c = 0;
    for (int i = tid; i < SS; i += TKT) c += (s[i] >= mid) ? 1 : 0;
#pragma unroll
    for (int m = 1; m < 64; m <<= 1) c += __shfl_xor(c, m, 64);
    if (lane == 0) wsum[wv] = c;
    __syncthreads();
    if (tid == 0) {
      int t = 0;
#pragma unroll
      for (int w = 0; w < TKT / 64; w++) t += wsum[w];
      cnt_sh = t;
    }
    __syncthreads();
    if (cnt_sh >= CANDN) lo = mid; else hi = mid - 1;
    __syncthreads();
  }
  const uint32_t T = lo;  // count(u>T) < CANDN <= count(u>=T)

  for (int i = tid; i < SS; i += TKT) {
    uint32_t u = s[i];
    if (u > T) {
      int p = atomicAdd(&counter, 1);
      cand[b * CANDN + p] = i;
    } else if (u == T) {
      int p = atomicAdd(&eqcount, 1);
      if (p < EQCAP) eqbuf[p] = i;
    }
  }
  __syncthreads();
  const int above = counter;
  const int rem = CANDN - above;
  int ec = eqcount; if (ec > EQCAP) ec = EQCAP;
  __syncthreads();
  for (int i = tid; i < ec; i += TKT) {
    int me = eqbuf[i];
    int rank = 0;
    for (int j = 0; j < ec; j++) rank += (eqbuf[j] < me) ? 1 : 0;
    if (rank < rem) {
      int p = atomicAdd(&counter, 1);
      cand[b * CANDN + p] = me;
    }
  }
}

// ---------------- stage-2: exact fp64 k for candidates ----------------
__global__ __launch_bounds__(256) void rescore_k(const float* __restrict__ key, const float* __restrict__ Wk,
                                                 const int* __restrict__ cand, double* __restrict__ kpart) {
  const int kc = blockIdx.x, h = blockIdx.y, b = blockIdx.z;
  const int d = threadIdx.x & 63, cg = threadIdx.x >> 6;
  __shared__ float wk[64 * 257];   // padded: 64 rows stride 257
  __shared__ float xs[24 * 256];
  for (int i = threadIdx.x; i < 64 * 256; i += 256)
    wk[(i >> 8) * 257 + (i & 255)] = Wk[(size_t)(h * 64 + (i >> 8)) * EE + kc * 256 + (i & 255)];
  for (int c0 = 0; c0 < CANDN; c0 += 24) {
    __syncthreads();
    for (int i = threadIdx.x; i < 24 * 256; i += 256) {
      int c = c0 + (i >> 8);
      xs[i] = key[((size_t)b * SS + cand[b * CANDN + c]) * EE + kc * 256 + (i & 255)];
    }
    __syncthreads();
    double acc[6] = {0, 0, 0, 0, 0, 0};
    for (int kk = 0; kk < 256; kk++) {
      double wv_ = (double)wk[d * 257 + kk];
#pragma unroll
      for (int j = 0; j < 6; j++)
        acc[j] += wv_ * (double)xs[(cg * 6 + j) * 256 + kk];
    }
#pragma unroll
    for (int j = 0; j < 6; j++) {
      int c = c0 + cg * 6 + j;
      kpart[(((size_t)kc * BB + b) * CANDN + c) * 1024 + h * 64 + d] = acc[j];
    }
  }
}

// exact fp64 candidate scores
__global__ __launch_bounds__(64) void score2_k(const double* __restrict__ kpart, const float* __restrict__ bk,
                                               double* __restrict__ sc2) {
  const int c = blockIdx.x, b = blockIdx.y;
  const int lane = threadIdx.x;
  double tot = 0.0;
  for (int h = 0; h < HH; h++) {
    double v = (double)bk[h * 64 + lane];
#pragma unroll
    for (int kc = 0; kc < 4; kc++)
      v += kpart[(((size_t)kc * BB + b) * CANDN + c) * 1024 + h * 64 + lane];
    double s = v * v;
#pragma unroll
    for (int m = 1; m < 64; m <<= 1) s += __shfl_xor(s, m, 64);
    tot += sqrt(s);
  }
  if (lane == 0) sc2[b * CANDN + c] = tot * (1.0 / 16.0);
}

// exact rank among candidates -> final idx in descending order (tie: lower index first)
__global__ __launch_bounds__(128) void topk2_k(const double* __restrict__ sc2, const int* __restrict__ cand,
                                               int* __restrict__ idxf) {
  const int b = blockIdx.x, t = threadIdx.x;
  if (t >= CANDN) return;
  double my = sc2[b * CANDN + t];
  int mi = cand[b * CANDN + t];
  int rank = 0;
  for (int j = 0; j < CANDN; j++) {
    double sj = sc2[b * CANDN + j];
    int ij = cand[b * CANDN + j];
    if (sj > my || (sj == my && ij < mi)) rank++;
  }
  if (rank < LL) idxf[b * LL + rank] = mi;
}

// gather value rows for the selected indices (fp32 -> bf16)
__global__ __launch_bounds__(256) void gatherx_k(const float* __restrict__ value, const int* __restrict__ idxf,
                                                 u16* __restrict__ xg) {
  const int r = blockIdx.x;  // b*64 + l
  const int b = r >> 6;
  const float* src = value + ((size_t)b * SS + idxf[r]) * EE;
  for (int i = threadIdx.x; i < EE; i += 256) xg[(size_t)r * EE + i] = f2b(src[i]);
}

// build k_sp[(b,h),l,d] (bf16) and v_spT[(b,h),d,l] (bf16)
__global__ __launch_bounds__(64) void gathersp_k(const u16* __restrict__ kb, const float* __restrict__ vg,
                                                 const int* __restrict__ idxf,
                                                 u16* __restrict__ ksp, u16* __restrict__ vspT) {
  const int g = blockIdx.x;  // (b*16+h)*64 + l
  const int l = g & 63, h = (g >> 6) & 15, b = g >> 10;
  const int d = threadIdx.x;
  ksp[(size_t)g * 64 + d] = kb[((size_t)b * SS + idxf[b * 64 + l]) * EE + h * 64 + d];
  vspT[((size_t)(b * 16 + h) * 64 + d) * 64 + l] = f2b(vg[((size_t)b * 64 + l) * EE + h * 64 + d]);
}

// ---------------- fused attention: QK^T -> softmax -> w out -> PV -> attn out ----------------
__global__ __launch_bounds__(256) void attn_k(const u16* __restrict__ qb, const u16* __restrict__ ksp,
                                              const u16* __restrict__ vspT,
                                              float* __restrict__ wout, u16* __restrict__ attnb) {
  __shared__ __align__(16) u16 qt[4096];
  __shared__ __align__(16) u16 kt[4096];
  __shared__ __align__(16) u16 vt[4096];
  __shared__ __align__(16) u16 wt[4096];
  const int tid = threadIdx.x;
  const int wv = tid >> 6, lane = tid & 63, quad = lane >> 4, l15 = lane & 15;
  const int s0 = blockIdx.x * 64;
  const int bh = blockIdx.y, b = bh >> 4, h = bh & 15;

  {
    const int bi0 = tid, bi1 = 256 + tid;
    const int r0 = bi0 >> 3, c0 = (bi0 & 7) ^ (r0 & 7);
    const int r1 = bi1 >> 3, c1 = (bi1 & 7) ^ (r1 & 7);
    const u16* qg = qb + ((size_t)b * SS + s0) * EE + h * 64;
    async16(qg + (size_t)r0 * EE + c0 * 8, qt + bi0 * 8);
    async16(qg + (size_t)r1 * EE + c1 * 8, qt + bi1 * 8);
    const u16* kg = ksp + (size_t)bh * 4096;
    async16(kg + r0 * 64 + c0 * 8, kt + bi0 * 8);
    async16(kg + r1 * 64 + c1 * 8, kt + bi1 * 8);
    const u16* vgp = vspT + (size_t)bh * 4096;
    async16(vgp + r0 * 64 + c0 * 8, vt + bi0 * 8);
    async16(vgp + r1 * 64 + c1 * 8, vt + bi1 * 8);
  }
  __syncthreads();

  f32x4 acc[4];
#pragma unroll
  for (int j = 0; j < 4; j++) acc[j] = (f32x4){0.f, 0.f, 0.f, 0.f};
  const int ar = 16 * wv + l15;
#pragma unroll
  for (int ks = 0; ks < 2; ks++) {
    const int cg = quad + ks * 4;
    short8 af = ((const short8*)qt)[ar * 8 + (cg ^ (ar & 7))];
#pragma unroll
    for (int j = 0; j < 4; j++) {
      int br = 16 * j + l15;
      short8 bf = ((const short8*)kt)[br * 8 + (cg ^ (br & 7))];
      acc[j] = __builtin_amdgcn_mfma_f32_16x16x32_bf16(af, bf, acc[j], 0, 0, 0);
    }
  }
#pragma unroll
  for (int j = 0; j < 4; j++) acc[j] *= 0.125f;  // 1/sqrt(D)

  float inv[4];
#pragma unroll
  for (int r = 0; r < 4; r++) {
    float m = fmaxf(fmaxf(acc[0][r], acc[1][r]), fmaxf(acc[2][r], acc[3][r]));
#pragma unroll
    for (int msk = 1; msk < 16; msk <<= 1) m = fmaxf(m, __shfl_xor(m, msk, 64));
    float e0 = __expf(acc[0][r] - m);
    float e1 = __expf(acc[1][r] - m);
    float e2 = __expf(acc[2][r] - m);
    float e3 = __expf(acc[3][r] - m);
    acc[0][r] = e0; acc[1][r] = e1; acc[2][r] = e2; acc[3][r] = e3;
    float s = e0 + e1 + e2 + e3;
#pragma unroll
    for (int msk = 1; msk < 16; msk <<= 1) s += __shfl_xor(s, msk, 64);
    inv[r] = 1.f / s;
  }

  const size_t wbase = ((size_t)bh * SS + s0 + 16 * wv) * 64;
#pragma unroll
  for (int j = 0; j < 4; j++) {
#pragma unroll
    for (int r = 0; r < 4; r++) {
      float val = acc[j][r] * inv[r];
      int rowl = quad * 4 + r;
      int l = 16 * j + l15;
      wout[wbase + (size_t)rowl * 64 + l] = val;
      int wr = 16 * wv + rowl;
      wt[wr * 64 + ((l >> 3) ^ (wr & 7)) * 8 + (l & 7)] = f2b(val);
    }
  }
  __syncthreads();

  f32x4 acc2[4];
#pragma unroll
  for (int j = 0; j < 4; j++) acc2[j] = (f32x4){0.f, 0.f, 0.f, 0.f};
#pragma unroll
  for (int ks = 0; ks < 2; ks++) {
    const int cg = quad + ks * 4;
    short8 af = ((const short8*)wt)[ar * 8 + (cg ^ (ar & 7))];
#pragma unroll
    for (int j = 0; j < 4; j++) {
      int br = 16 * j + l15;
      short8 bf = ((const short8*)vt)[br * 8 + (cg ^ (br & 7))];
      acc2[j] = __builtin_amdgcn_mfma_f32_16x16x32_bf16(af, bf, acc2[j], 0, 0, 0);
    }
  }
#pragma unroll
  for (int j = 0; j < 4; j++)
#pragma unroll
    for (int r = 0; r < 4; r++)
      attnb[((size_t)b * SS + s0 + 16 * wv + quad * 4 + r) * EE + h * 64 + 16 * j + l15] = f2b(acc2[j][r]);
}

extern "C" void kernel_launch(void* const* d_in, const int* in_sizes, int n_in,
                              void* d_out, int out_size, void* d_ws, size_t ws_size,
                              hipStream_t stream) {
  (void)in_sizes; (void)n_in; (void)out_size; (void)ws_size;
  const float* query = (const float*)d_in[0];
  const float* key   = (const float*)d_in[1];
  const float* value = (const float*)d_in[2];
  const float* Wq = (const float*)d_in[3];
  const float* bq = (const float*)d_in[4];
  const float* Wk = (const float*)d_in[5];
  const float* bk = (const float*)d_in[6];
  const float* Wv = (const float*)d_in[7];
  const float* bv = (const float*)d_in[8];
  const float* Wo = (const float*)d_in[9];
  const float* bo = (const float*)d_in[10];
  float* out = (float*)d_out;
  float* wout = out + (size_t)BB * SS * EE;

  char* p = (char*)d_ws;
  auto alloc = [&](size_t n) { char* r = p; p += (n + 255) & ~(size_t)255; return r; };
  u16* qbf = (u16*)alloc((size_t)BB * SS * EE * 2);   // query bf16; reused later as attn output
  u16* kbf = (u16*)alloc((size_t)BB * SS * EE * 2);
  u16* wqb = (u16*)alloc((size_t)EE * EE * 2);
  u16* wkb = (u16*)alloc((size_t)EE * EE * 2);
  u16* wvb = (u16*)alloc((size_t)EE * EE * 2);
  u16* wob = (u16*)alloc((size_t)EE * EE * 2);
  u16* qb  = (u16*)alloc((size_t)BB * SS * EE * 2);
  u16* kb  = (u16*)alloc((size_t)BB * SS * EE * 2);
  float*  sc    = (float*)alloc((size_t)BB * SS * 4);
  int*    cand  = (int*)alloc(BB * CANDN * 4);
  double* kpart = (double*)alloc((size_t)4 * BB * CANDN * 1024 * 8);
  double* sc2   = (double*)alloc(BB * CANDN * 8);
  int*    idxf  = (int*)alloc(BB * LL * 4);
  u16*    xg    = (u16*)alloc((size_t)BB * LL * EE * 2);
  float*  vg    = (float*)alloc((size_t)BB * LL * EE * 4);
  u16*    ksp   = (u16*)alloc((size_t)BB * HH * LL * DD * 2);
  u16*    vspT  = (u16*)alloc((size_t)BB * HH * DD * LL * 2);
  u16*    attnb = qbf;  // reuse: query_bf16 dead after Q GEMM

  const int M = BB * SS;
  const size_t g128_lds = 65536;  // 4 buffers x (128x32 A + 128x32 B) u16

  cvt_bf16_k<<<(M * EE / 4 + 255) / 256, 256, 0, stream>>>(query, qbf, M * EE / 4);
  cvt_bf16_k<<<(M * EE / 4 + 255) / 256, 256, 0, stream>>>(key, kbf, M * EE / 4);
  cvt_bf16_k<<<(EE * EE / 4 + 255) / 256, 256, 0, stream>>>(Wq, wqb, EE * EE / 4);
  cvt_bf16_k<<<(EE * EE / 4 + 255) / 256, 256, 0, stream>>>(Wk, wkb, EE * EE / 4);
  cvt_bf16_k<<<(EE * EE / 4 + 255) / 256, 256, 0, stream>>>(Wv, wvb, EE * EE / 4);
  cvt_bf16_k<<<(EE * EE / 4 + 255) / 256, 256, 0, stream>>>(Wo, wob, EE * EE / 4);
  hipMemsetAsync(sc, 0, (size_t)M * 4, stream);

  // merged Q+K projections: by < 256 -> Q set; else K set (+fused scores)
  gemm128<<<dim3(EE / 128, 2 * M / 128), 256, g128_lds, stream>>>(
      qbf, wqb, bq, nullptr, qb, nullptr,
      kbf, wkb, bk, nullptr, kb, sc, M / 128, EE);

  topk1_k<<<BB, TKT, 0, stream>>>(sc, cand);
  rescore_k<<<dim3(4, HH, BB), 256, 0, stream>>>(key, Wk, cand, kpart);
  score2_k<<<dim3(CANDN, BB), 64, 0, stream>>>(kpart, bk, sc2);
  topk2_k<<<BB, 128, 0, stream>>>(sc2, cand, idxf);

  gatherx_k<<<BB * LL, 256, 0, stream>>>(value, idxf, xg);
  gemm128<<<dim3(EE / 128, BB * LL / 128), 256, g128_lds, stream>>>(
      xg, wvb, bv, vg, nullptr, nullptr,
      xg, wvb, bv, vg, nullptr, nullptr, BB * LL / 128, EE);  // V on 256 rows
  gathersp_k<<<BB * HH * LL, 64, 0, stream>>>(kb, vg, idxf, ksp, vspT);

  attn_k<<<dim3(SS / 64, BB * HH), 256, 0, stream>>>(qb, ksp, vspT, wout, attnb);

  gemm128<<<dim3(EE / 128, M / 128), 256, g128_lds, stream>>>(
      attnb, wob, bo, out, nullptr, nullptr,
      attnb, wob, bo, out, nullptr, nullptr, M / 128, EE);   // output projection
}

// Round 11
// 920.821 us; speedup vs baseline: 1.1003x; 1.1003x over previous
//
#include <hip/hip_runtime.h>
#include <cstdint>

typedef unsigned short u16;
typedef __attribute__((ext_vector_type(8))) short short8;
typedef __attribute__((ext_vector_type(4))) float f32x4;

#define AS1 __attribute__((address_space(1)))
#define AS3 __attribute__((address_space(3)))

#define BB 4
#define SS 8192
#define EE 1024
#define HH 16
#define DD 64
#define LL 64
#define CANDN 96

__device__ __forceinline__ void async16(const void* g, void* l) {
  __builtin_amdgcn_global_load_lds((const AS1 uint32_t*)g, (AS3 uint32_t*)l, 16, 0, 0);
}
__device__ __forceinline__ u16 f2b(float f) {  // RNE fp32 -> bf16
  uint32_t u = __float_as_uint(f);
  return (u16)((u + 0x7fffu + ((u >> 16) & 1u)) >> 16);
}
__device__ __forceinline__ float b2f(u16 h) { return __uint_as_float(((uint32_t)h) << 16); }

// ---------------- fp32 -> bf16 bulk convert (n divisible by 4) ----------------
__global__ __launch_bounds__(256) void cvt_bf16_k(const float* __restrict__ in, u16* __restrict__ out, int n4) {
  int i = blockIdx.x * 256 + threadIdx.x;
  if (i >= n4) return;
  float4 v = ((const float4*)in)[i];
  ushort4 o;
  o.x = f2b(v.x); o.y = f2b(v.y); o.z = f2b(v.z); o.w = f2b(v.w);
  ((ushort4*)out)[i] = o;
}

// ---------------- NT GEMM v6 (gemm8p): 256x256 8-phase-style counted pipeline ----------------
// C[m,n] = sum_k A[m,k]*W[n,k] + bias[n]. BM=BN=256, BK=64, 512 thr = 8 waves (2m x 4n),
// per-wave C 128x64 (acc[8][4] f32x4 = 128 VGPR). LDS 128 KB: per dbuf, A = 4 chunks x
// (64 rows x 64 K) bf16, B = 4 chunks x (64 N-rows x 64 K). Granule-XOR swizzle g^(row&7)
// on pre-swizzled global SOURCE (rule #21; 0 bank conflicts measured R8-R10).
// R10 post-mortem: all 2-phase variants cap at ~530-580 TF (m233 ceiling). This is the
// m201-style fine interleave: per K-tile tau, 4 phases = 4 C-quadrants (16 MFMA each):
//   P1: read A(rh0) 8x + B(ch0) 4x | stage (tau+1)A1A3 -> dbuf[o] | SBAR | MFMA Q(0,0)
//   P2: read B(ch1) 4x            | stage (tau+2)A0A2 -> dbuf[d] | vmcnt(10) SBAR | Q(0,1)
//   P3: read A(rh1) 8x            | stage (tau+2)B0B1 -> dbuf[d] | SBAR | Q(1,1)
//   P4: (regs only)               | stage (tau+2)B2B3 -> dbuf[d] | vmcnt(8) SBAR | Q(1,0)
// Raw s_barrier (NOT __syncthreads: it drains vmcnt) + sched_barrier(0) fences.
// Region safety: each stage target's last ds_reads complete before the barrier preceding
// the stage issue (A1A3[o] read at [tau-1 P3]; A0A2[d] at [tau P1]; B[d] at [tau P1/P2]).
// Ledger (2 loads per stage group, per thread): issue order ... [t-2 P2] tA0A2, [t-2 P3]
// tB0B1, [t-2 P4] tB2B3, [t-1 P1] tA1A3, [t-1 P2] (t+1)A0A2, ... vmcnt completes in issue
// order (m135). End-P4 wait (for t+1 P1 reads: needs (t+1)A0A2+B all landed): newer =
// (t+1)A1A3 + (t+2){A0A2,B0B1,B2B3} = 8 -> vmcnt(8); epilogue 2. End-P2 wait (for own
// A1A3, staged [t-1 P1]): newer = (t+1){A0A2,B0B1,B2B3,A1A3} + (t+2)A0A2 = 10 ->
// vmcnt(10); epilogue 8 then 0. Prologue stages t0{A0A2,B01,B23,A1A3}+t1{A0A2,B01,B23}
// (14 loads) then vmcnt(8) = steady-state invariant.
// Optional scA epilogue (K-proj): wave's 64 cols = 1 head; 16-lane shuffle-reduce of
// sum((v+bias)^2), one atomicAdd(sqrt/16) per row -> replaces scores_k.
#define SBAR() { __builtin_amdgcn_sched_barrier(0); __builtin_amdgcn_s_barrier(); __builtin_amdgcn_sched_barrier(0); }

__global__ __launch_bounds__(512) void gemm8p(const u16* __restrict__ A, const u16* __restrict__ W,
                                              const float* __restrict__ bias,
                                              float* __restrict__ Cf, u16* __restrict__ Cb,
                                              float* __restrict__ scA, int K) {
  extern __shared__ __align__(16) u16 lds_[];  // A: [2][4][64*64] then B: [2][4][64*64]
  const int tid = threadIdx.x;
  const int wv = tid >> 6, lane = tid & 63;
  const int quad = lane >> 4, l15 = lane & 15;
  const int wm = wv >> 2, wn = wv & 3;   // 2 x 4 waves; per-wave out 128x64

  const int nwg = gridDim.x * gridDim.y;
  int g = blockIdx.y * gridDim.x + blockIdx.x;
  int bx = blockIdx.x, by = blockIdx.y;
  if ((nwg & 7) == 0) {
    const int chunk = nwg >> 3;
    const int v = (g & 7) * chunk + (g >> 3);
    bx = v % gridDim.x;
    by = v / gridDim.x;
  }
  const int mt = by * 256, nt = bx * 256;

  // staging addressing: thread covers row rl of a 64-row chunk, phys granule tid&7,
  // source logical granule (tid&7)^(rl&7)  (dest is linear: base + tid*16B)
  const int rl = tid >> 3;
  const int g8 = (((tid & 7) ^ (rl & 7))) * 8;
  const u16* sA[4]; const u16* sB[4];
#pragma unroll
  for (int c = 0; c < 4; c++) {
    sA[c] = A + (size_t)(mt + c * 64 + rl) * K + g8;
    sB[c] = W + (size_t)(nt + c * 64 + rl) * K + g8;
  }
  const short8* L8 = (const short8*)lds_;

  f32x4 acc[8][4];
#pragma unroll
  for (int i = 0; i < 8; i++)
#pragma unroll
    for (int j = 0; j < 4; j++) acc[i][j] = (f32x4){0.f, 0.f, 0.f, 0.f};

  const int NT = K >> 6;  // 16 for K=1024
  const int gp0 = (0 * 4 + quad) ^ (l15 & 7);
  const int gp1 = (1 * 4 + quad) ^ (l15 & 7);

#define STA(T, D, C) async16(sA[C] + (T) * 64, lds_ + (D) * 16384 + (C) * 4096 + tid * 8)
#define STB(T, D, C) async16(sB[C] + (T) * 64, lds_ + 32768 + (D) * 16384 + (C) * 4096 + tid * 8)
  // A frag read: chunk 2*wm+RH, row 16*i+l15, granule gp; B: chunk wn, row CH*32+16*j+l15
#define RDA(D, RH) { _Pragma("unroll") for (int i = 0; i < 4; i++) { \
    const int bidx = (D) * 2048 + (2 * wm + (RH)) * 512 + (16 * i + l15) * 8; \
    af[0][i] = L8[bidx + gp0]; af[1][i] = L8[bidx + gp1]; } }
#define RDB(D, CH, BF) { _Pragma("unroll") for (int j = 0; j < 2; j++) { \
    const int bidx = 4096 + (D) * 2048 + wn * 512 + ((CH) * 32 + 16 * j + l15) * 8; \
    BF[0][j] = L8[bidx + gp0]; BF[1][j] = L8[bidx + gp1]; } }
#define MFMA_Q(RH, CH, BF) { __builtin_amdgcn_s_setprio(1); \
    _Pragma("unroll") for (int i = 0; i < 4; i++) \
      _Pragma("unroll") for (int j = 0; j < 2; j++) { \
        acc[(RH)*4+i][(CH)*2+j] = __builtin_amdgcn_mfma_f32_16x16x32_bf16(af[0][i], BF[0][j], acc[(RH)*4+i][(CH)*2+j], 0, 0, 0); \
        acc[(RH)*4+i][(CH)*2+j] = __builtin_amdgcn_mfma_f32_16x16x32_bf16(af[1][i], BF[1][j], acc[(RH)*4+i][(CH)*2+j], 0, 0, 0); } \
    __builtin_amdgcn_s_setprio(0); }

  // prologue: t0 {A0A2, B0B1, B2B3, A1A3} + t1 {A0A2, B0B1, B2B3}
  STA(0, 0, 0); STA(0, 0, 2);
  STB(0, 0, 0); STB(0, 0, 1);
  STB(0, 0, 2); STB(0, 0, 3);
  STA(0, 0, 1); STA(0, 0, 3);
  if (NT > 1) {
    STA(1, 1, 0); STA(1, 1, 2);
    STB(1, 1, 0); STB(1, 1, 1);
    STB(1, 1, 2); STB(1, 1, 3);
  }
  asm volatile("s_waitcnt vmcnt(8)" ::: "memory");
  SBAR();

  for (int kt = 0; kt < NT; ++kt) {
    const int d = kt & 1, o = d ^ 1;
    short8 af[2][4], bf0[2][2], bf1[2][2];
    // P1: quadrant (0,0)
    RDA(d, 0);
    RDB(d, 0, bf0);
    if (kt + 1 < NT) { STA(kt + 1, o, 1); STA(kt + 1, o, 3); }
    SBAR();
    MFMA_Q(0, 0, bf0);
    // P2: quadrant (0,1)
    RDB(d, 1, bf1);
    if (kt + 2 < NT) { STA(kt + 2, d, 0); STA(kt + 2, d, 2); }
    if (kt < NT - 2)       { asm volatile("s_waitcnt vmcnt(10)" ::: "memory"); }
    else if (kt == NT - 2) { asm volatile("s_waitcnt vmcnt(8)" ::: "memory"); }
    else                   { asm volatile("s_waitcnt vmcnt(0)" ::: "memory"); }
    SBAR();
    MFMA_Q(0, 1, bf1);
    // P3: quadrant (1,1)
    RDA(d, 1);
    if (kt + 2 < NT) { STB(kt + 2, d, 0); STB(kt + 2, d, 1); }
    SBAR();
    MFMA_Q(1, 1, bf1);
    // P4: quadrant (1,0) — regs only
    if (kt + 2 < NT) { STB(kt + 2, d, 2); STB(kt + 2, d, 3); }
    if (kt + 2 < NT)      { asm volatile("s_waitcnt vmcnt(8)" ::: "memory"); SBAR(); }
    else if (kt + 1 < NT) { asm volatile("s_waitcnt vmcnt(2)" ::: "memory"); SBAR(); }
    MFMA_Q(1, 0, bf0);
  }

  float bs[4];
#pragma unroll
  for (int j = 0; j < 4; j++) bs[j] = bias[nt + wn * 64 + 16 * j + l15];
#pragma unroll
  for (int i = 0; i < 8; i++) {
#pragma unroll
    for (int r = 0; r < 4; r++) {
      const int gm = mt + wm * 128 + 16 * i + quad * 4 + r;
      float nrm = 0.f;
#pragma unroll
      for (int j = 0; j < 4; j++) {
        float v = acc[i][j][r] + bs[j];
        const int gn = nt + wn * 64 + 16 * j + l15;
        if (Cf) Cf[(size_t)gm * EE + gn] = v;
        if (Cb) Cb[(size_t)gm * EE + gn] = f2b(v);
        nrm += v * v;
      }
      if (scA) {
#pragma unroll
        for (int m = 1; m < 16; m <<= 1) nrm += __shfl_xor(nrm, m, 64);
        if (l15 == 0) atomicAdd(&scA[gm], sqrtf(nrm) * (1.f / 16.f));
      }
    }
  }
}

// ---------------- stage-1 topk: exact top-96 set per batch (order-free) ----------------
#define TKT 1024
#define EQCAP 256
__global__ __launch_bounds__(TKT) void topk1_k(const float* __restrict__ sc, int* __restrict__ cand) {
  const int b = blockIdx.x;
  __shared__ uint32_t s[SS];
  __shared__ int wsum[TKT / 64];
  __shared__ int cnt_sh;
  __shared__ int counter, eqcount;
  __shared__ int eqbuf[EQCAP];
  const int tid = threadIdx.x;
  const int lane = tid & 63, wv = tid >> 6;
  for (int i = tid; i < SS; i += TKT) s[i] = __float_as_uint(sc[b * SS + i]);
  if (tid == 0) { counter = 0; eqcount = 0; }
  __syncthreads();

  uint32_t lo = 0u, hi = 0x7f7fffffu;
  while (lo < hi) {
    uint32_t mid = lo + ((hi - lo + 1) >> 1);
    int c = 0;
    for (int i = tid; i < SS; i += TKT) c += (s[i] >= mid) ? 1 : 0;
#pragma unroll
    for (int m = 1; m < 64; m <<= 1) c += __shfl_xor(c, m, 64);
    if (lane == 0) wsum[wv] = c;
    __syncthreads();
    if (tid == 0) {
      int t = 0;
#pragma unroll
      for (int w = 0; w < TKT / 64; w++) t += wsum[w];
      cnt_sh = t;
    }
    __syncthreads();
    if (cnt_sh >= CANDN) lo = mid; else hi = mid - 1;
    __syncthreads();
  }
  const uint32_t T = lo;  // count(u>T) < CANDN <= count(u>=T)

  for (int i = tid; i < SS; i += TKT) {
    uint32_t u = s[i];
    if (u > T) {
      int p = atomicAdd(&counter, 1);
      cand[b * CANDN + p] = i;
    } else if (u == T) {
      int p = atomicAdd(&eqcount, 1);
      if (p < EQCAP) eqbuf[p] = i;
    }
  }
  __syncthreads();
  const int above = counter;
  const int rem = CANDN - above;
  int ec = eqcount; if (ec > EQCAP) ec = EQCAP;
  __syncthreads();
  for (int i = tid; i < ec; i += TKT) {
    int me = eqbuf[i];
    int rank = 0;
    for (int j = 0; j < ec; j++) rank += (eqbuf[j] < me) ? 1 : 0;
    if (rank < rem) {
      int p = atomicAdd(&counter, 1);
      cand[b * CANDN + p] = me;
    }
  }
}

// ---------------- stage-2: exact fp64 k for candidates ----------------
__global__ __launch_bounds__(256) void rescore_k(const float* __restrict__ key, const float* __restrict__ Wk,
                                                 const int* __restrict__ cand, double* __restrict__ kpart) {
  const int kc = blockIdx.x, h = blockIdx.y, b = blockIdx.z;
  const int d = threadIdx.x & 63, cg = threadIdx.x >> 6;
  __shared__ float wk[64 * 257];   // padded: 64 rows stride 257
  __shared__ float xs[24 * 256];
  for (int i = threadIdx.x; i < 64 * 256; i += 256)
    wk[(i >> 8) * 257 + (i & 255)] = Wk[(size_t)(h * 64 + (i >> 8)) * EE + kc * 256 + (i & 255)];
  for (int c0 = 0; c0 < CANDN; c0 += 24) {
    __syncthreads();
    for (int i = threadIdx.x; i < 24 * 256; i += 256) {
      int c = c0 + (i >> 8);
      xs[i] = key[((size_t)b * SS + cand[b * CANDN + c]) * EE + kc * 256 + (i & 255)];
    }
    __syncthreads();
    double acc[6] = {0, 0, 0, 0, 0, 0};
    for (int kk = 0; kk < 256; kk++) {
      double wv_ = (double)wk[d * 257 + kk];
#pragma unroll
      for (int j = 0; j < 6; j++)
        acc[j] += wv_ * (double)xs[(cg * 6 + j) * 256 + kk];
    }
#pragma unroll
    for (int j = 0; j < 6; j++) {
      int c = c0 + cg * 6 + j;
      kpart[(((size_t)kc * BB + b) * CANDN + c) * 1024 + h * 64 + d] = acc[j];
    }
  }
}

// exact fp64 candidate scores
__global__ __launch_bounds__(64) void score2_k(const double* __restrict__ kpart, const float* __restrict__ bk,
                                               double* __restrict__ sc2) {
  const int c = blockIdx.x, b = blockIdx.y;
  const int lane = threadIdx.x;
  double tot = 0.0;
  for (int h = 0; h < HH; h++) {
    double v = (double)bk[h * 64 + lane];
#pragma unroll
    for (int kc = 0; kc < 4; kc++)
      v += kpart[(((size_t)kc * BB + b) * CANDN + c) * 1024 + h * 64 + lane];
    double s = v * v;
#pragma unroll
    for (int m = 1; m < 64; m <<= 1) s += __shfl_xor(s, m, 64);
    tot += sqrt(s);
  }
  if (lane == 0) sc2[b * CANDN + c] = tot * (1.0 / 16.0);
}

// exact rank among candidates -> final idx in descending order (tie: lower index first)
__global__ __launch_bounds__(128) void topk2_k(const double* __restrict__ sc2, const int* __restrict__ cand,
                                               int* __restrict__ idxf) {
  const int b = blockIdx.x, t = threadIdx.x;
  if (t >= CANDN) return;
  double my = sc2[b * CANDN + t];
  int mi = cand[b * CANDN + t];
  int rank = 0;
  for (int j = 0; j < CANDN; j++) {
    double sj = sc2[b * CANDN + j];
    int ij = cand[b * CANDN + j];
    if (sj > my || (sj == my && ij < mi)) rank++;
  }
  if (rank < LL) idxf[b * LL + rank] = mi;
}

// gather value rows for the selected indices (fp32 -> bf16)
__global__ __launch_bounds__(256) void gatherx_k(const float* __restrict__ value, const int* __restrict__ idxf,
                                                 u16* __restrict__ xg) {
  const int r = blockIdx.x;  // b*64 + l
  const int b = r >> 6;
  const float* src = value + ((size_t)b * SS + idxf[r]) * EE;
  for (int i = threadIdx.x; i < EE; i += 256) xg[(size_t)r * EE + i] = f2b(src[i]);
}

// build k_sp[(b,h),l,d] (bf16) and v_spT[(b,h),d,l] (bf16)
__global__ __launch_bounds__(64) void gathersp_k(const u16* __restrict__ kb, const float* __restrict__ vg,
                                                 const int* __restrict__ idxf,
                                                 u16* __restrict__ ksp, u16* __restrict__ vspT) {
  const int g = blockIdx.x;  // (b*16+h)*64 + l
  const int l = g & 63, h = (g >> 6) & 15, b = g >> 10;
  const int d = threadIdx.x;
  ksp[(size_t)g * 64 + d] = kb[((size_t)b * SS + idxf[b * 64 + l]) * EE + h * 64 + d];
  vspT[((size_t)(b * 16 + h) * 64 + d) * 64 + l] = f2b(vg[((size_t)b * 64 + l) * EE + h * 64 + d]);
}

// ---------------- fused attention: QK^T -> softmax -> w out -> PV -> attn out ----------------
__global__ __launch_bounds__(256) void attn_k(const u16* __restrict__ qb, const u16* __restrict__ ksp,
                                              const u16* __restrict__ vspT,
                                              float* __restrict__ wout, u16* __restrict__ attnb) {
  __shared__ __align__(16) u16 qt[4096];
  __shared__ __align__(16) u16 kt[4096];
  __shared__ __align__(16) u16 vt[4096];
  __shared__ __align__(16) u16 wt[4096];
  const int tid = threadIdx.x;
  const int wv = tid >> 6, lane = tid & 63, quad = lane >> 4, l15 = lane & 15;
  const int s0 = blockIdx.x * 64;
  const int bh = blockIdx.y, b = bh >> 4, h = bh & 15;

  {
    const int bi0 = tid, bi1 = 256 + tid;
    const int r0 = bi0 >> 3, c0 = (bi0 & 7) ^ (r0 & 7);
    const int r1 = bi1 >> 3, c1 = (bi1 & 7) ^ (r1 & 7);
    const u16* qg = qb + ((size_t)b * SS + s0) * EE + h * 64;
    async16(qg + (size_t)r0 * EE + c0 * 8, qt + bi0 * 8);
    async16(qg + (size_t)r1 * EE + c1 * 8, qt + bi1 * 8);
    const u16* kg = ksp + (size_t)bh * 4096;
    async16(kg + r0 * 64 + c0 * 8, kt + bi0 * 8);
    async16(kg + r1 * 64 + c1 * 8, kt + bi1 * 8);
    const u16* vgp = vspT + (size_t)bh * 4096;
    async16(vgp + r0 * 64 + c0 * 8, vt + bi0 * 8);
    async16(vgp + r1 * 64 + c1 * 8, vt + bi1 * 8);
  }
  __syncthreads();

  f32x4 acc[4];
#pragma unroll
  for (int j = 0; j < 4; j++) acc[j] = (f32x4){0.f, 0.f, 0.f, 0.f};
  const int ar = 16 * wv + l15;
#pragma unroll
  for (int ks = 0; ks < 2; ks++) {
    const int cg = quad + ks * 4;
    short8 af = ((const short8*)qt)[ar * 8 + (cg ^ (ar & 7))];
#pragma unroll
    for (int j = 0; j < 4; j++) {
      int br = 16 * j + l15;
      short8 bf = ((const short8*)kt)[br * 8 + (cg ^ (br & 7))];
      acc[j] = __builtin_amdgcn_mfma_f32_16x16x32_bf16(af, bf, acc[j], 0, 0, 0);
    }
  }
#pragma unroll
  for (int j = 0; j < 4; j++) acc[j] *= 0.125f;  // 1/sqrt(D)

  float inv[4];
#pragma unroll
  for (int r = 0; r < 4; r++) {
    float m = fmaxf(fmaxf(acc[0][r], acc[1][r]), fmaxf(acc[2][r], acc[3][r]));
#pragma unroll
    for (int msk = 1; msk < 16; msk <<= 1) m = fmaxf(m, __shfl_xor(m, msk, 64));
    float e0 = __expf(acc[0][r] - m);
    float e1 = __expf(acc[1][r] - m);
    float e2 = __expf(acc[2][r] - m);
    float e3 = __expf(acc[3][r] - m);
    acc[0][r] = e0; acc[1][r] = e1; acc[2][r] = e2; acc[3][r] = e3;
    float s = e0 + e1 + e2 + e3;
#pragma unroll
    for (int msk = 1; msk < 16; msk <<= 1) s += __shfl_xor(s, msk, 64);
    inv[r] = 1.f / s;
  }

  const size_t wbase = ((size_t)bh * SS + s0 + 16 * wv) * 64;
#pragma unroll
  for (int j = 0; j < 4; j++) {
#pragma unroll
    for (int r = 0; r < 4; r++) {
      float val = acc[j][r] * inv[r];
      int rowl = quad * 4 + r;
      int l = 16 * j + l15;
      wout[wbase + (size_t)rowl * 64 + l] = val;
      int wr = 16 * wv + rowl;
      wt[wr * 64 + ((l >> 3) ^ (wr & 7)) * 8 + (l & 7)] = f2b(val);
    }
  }
  __syncthreads();

  f32x4 acc2[4];
#pragma unroll
  for (int j = 0; j < 4; j++) acc2[j] = (f32x4){0.f, 0.f, 0.f, 0.f};
#pragma unroll
  for (int ks = 0; ks < 2; ks++) {
    const int cg = quad + ks * 4;
    short8 af = ((const short8*)wt)[ar * 8 + (cg ^ (ar & 7))];
#pragma unroll
    for (int j = 0; j < 4; j++) {
      int br = 16 * j + l15;
      short8 bf = ((const short8*)vt)[br * 8 + (cg ^ (br & 7))];
      acc2[j] = __builtin_amdgcn_mfma_f32_16x16x32_bf16(af, bf, acc2[j], 0, 0, 0);
    }
  }
#pragma unroll
  for (int j = 0; j < 4; j++)
#pragma unroll
    for (int r = 0; r < 4; r++)
      attnb[((size_t)b * SS + s0 + 16 * wv + quad * 4 + r) * EE + h * 64 + 16 * j + l15] = f2b(acc2[j][r]);
}

extern "C" void kernel_launch(void* const* d_in, const int* in_sizes, int n_in,
                              void* d_out, int out_size, void* d_ws, size_t ws_size,
                              hipStream_t stream) {
  (void)in_sizes; (void)n_in; (void)out_size; (void)ws_size;
  const float* query = (const float*)d_in[0];
  const float* key   = (const float*)d_in[1];
  const float* value = (const float*)d_in[2];
  const float* Wq = (const float*)d_in[3];
  const float* bq = (const float*)d_in[4];
  const float* Wk = (const float*)d_in[5];
  const float* bk = (const float*)d_in[6];
  const float* Wv = (const float*)d_in[7];
  const float* bv = (const float*)d_in[8];
  const float* Wo = (const float*)d_in[9];
  const float* bo = (const float*)d_in[10];
  float* out = (float*)d_out;
  float* wout = out + (size_t)BB * SS * EE;

  char* p = (char*)d_ws;
  auto alloc = [&](size_t n) { char* r = p; p += (n + 255) & ~(size_t)255; return r; };
  u16* qbf = (u16*)alloc((size_t)BB * SS * EE * 2);   // query bf16; reused later as attn output
  u16* kbf = (u16*)alloc((size_t)BB * SS * EE * 2);
  u16* wqb = (u16*)alloc((size_t)EE * EE * 2);
  u16* wkb = (u16*)alloc((size_t)EE * EE * 2);
  u16* wvb = (u16*)alloc((size_t)EE * EE * 2);
  u16* wob = (u16*)alloc((size_t)EE * EE * 2);
  u16* qb  = (u16*)alloc((size_t)BB * SS * EE * 2);
  u16* kb  = (u16*)alloc((size_t)BB * SS * EE * 2);
  float*  sc    = (float*)alloc((size_t)BB * SS * 4);
  int*    cand  = (int*)alloc(BB * CANDN * 4);
  double* kpart = (double*)alloc((size_t)4 * BB * CANDN * 1024 * 8);
  double* sc2   = (double*)alloc(BB * CANDN * 8);
  int*    idxf  = (int*)alloc(BB * LL * 4);
  u16*    xg    = (u16*)alloc((size_t)BB * LL * EE * 2);
  float*  vg    = (float*)alloc((size_t)BB * LL * EE * 4);
  u16*    ksp   = (u16*)alloc((size_t)BB * HH * LL * DD * 2);
  u16*    vspT  = (u16*)alloc((size_t)BB * HH * DD * LL * 2);
  u16*    attnb = qbf;  // reuse: query_bf16 dead after Q GEMM

  const int M = BB * SS;
  const size_t g8p_lds = 131072;  // 2 dbuf x (A 32KB + B 32KB)

  cvt_bf16_k<<<(M * EE / 4 + 255) / 256, 256, 0, stream>>>(query, qbf, M * EE / 4);
  cvt_bf16_k<<<(M * EE / 4 + 255) / 256, 256, 0, stream>>>(key, kbf, M * EE / 4);
  cvt_bf16_k<<<(EE * EE / 4 + 255) / 256, 256, 0, stream>>>(Wq, wqb, EE * EE / 4);
  cvt_bf16_k<<<(EE * EE / 4 + 255) / 256, 256, 0, stream>>>(Wk, wkb, EE * EE / 4);
  cvt_bf16_k<<<(EE * EE / 4 + 255) / 256, 256, 0, stream>>>(Wv, wvb, EE * EE / 4);
  cvt_bf16_k<<<(EE * EE / 4 + 255) / 256, 256, 0, stream>>>(Wo, wob, EE * EE / 4);
  hipMemsetAsync(sc, 0, (size_t)M * 4, stream);

  dim3 gg(EE / 256, M / 256);
  gemm8p<<<gg, 512, g8p_lds, stream>>>(qbf, wqb, bq, nullptr, qb, nullptr, EE);  // Q projection
  gemm8p<<<gg, 512, g8p_lds, stream>>>(kbf, wkb, bk, nullptr, kb, sc, EE);       // K proj + fused scores

  topk1_k<<<BB, TKT, 0, stream>>>(sc, cand);
  rescore_k<<<dim3(4, HH, BB), 256, 0, stream>>>(key, Wk, cand, kpart);
  score2_k<<<dim3(CANDN, BB), 64, 0, stream>>>(kpart, bk, sc2);
  topk2_k<<<BB, 128, 0, stream>>>(sc2, cand, idxf);

  gatherx_k<<<BB * LL, 256, 0, stream>>>(value, idxf, xg);
  gemm8p<<<dim3(EE / 256, BB * LL / 256), 512, g8p_lds, stream>>>(xg, wvb, bv, vg, nullptr, nullptr, EE);  // V
  gathersp_k<<<BB * HH * LL, 64, 0, stream>>>(kb, vg, idxf, ksp, vspT);

  attn_k<<<dim3(SS / 64, BB * HH), 256, 0, stream>>>(qb, ksp, vspT, wout, attnb);

  gemm8p<<<gg, 512, g8p_lds, stream>>>(attnb, wob, bo, out, nullptr, nullptr, EE); // output projection
}